// Round 1
// baseline (76.170 us; speedup 1.0000x reference)
//
#include <hip/hip_runtime.h>

#define B 32
#define V 256
#define F 128
#define P 64

#define LOG2E 1.44269504088896340736f

// One block per (b, f) pair: 4096 blocks x 256 threads (thread = v).
// Wave 0 does the 64-wide softmax (P == wavefront size) into LDS, then all
// 256 threads run the P-loop with LDS broadcast reads of (q, amp).
__global__ __launch_bounds__(256) void extraction_kernel(
    const float* __restrict__ q2,      // (B, P)
    const float* __restrict__ logits,  // (B, 1, F, P)
    const float* __restrict__ vol,     // (V, 1)
    const float* __restrict__ filt,    // (1, F)
    const float* __restrict__ sigma_p, // (1,)
    float* __restrict__ out)           // (B, V, F)
{
    const int bid = blockIdx.x;        // = b * F + f
    const int b   = bid >> 7;          // / F
    const int f   = bid & (F - 1);
    const int tid = threadIdx.x;       // = v

    __shared__ float q_s[P];
    __shared__ float amp_s[P];

    // Prologue: threads 0..63 (exactly one wave) compute softmax of
    // logits[b, 0, f, :] and stage q2[b, :].
    if (tid < P) {
        float l = logits[bid * P + tid];
        float m = l;
        #pragma unroll
        for (int off = 32; off > 0; off >>= 1)
            m = fmaxf(m, __shfl_xor(m, off, 64));
        float e = __builtin_amdgcn_exp2f((l - m) * LOG2E);
        float s = e;
        #pragma unroll
        for (int off = 32; off > 0; off >>= 1)
            s += __shfl_xor(s, off, 64);
        amp_s[tid] = e / s;
        q_s[tid]   = q2[b * P + tid];
    }
    __syncthreads();

    const float sig = sigma_p[0];                 // wave-uniform scalar
    const float inv = 1.0f / (sig + 0.001f);
    const float kk  = -0.5f * LOG2E * inv * inv;  // exp(-0.5 (d*inv)^2) = 2^(kk*d^2)

    const float x = vol[tid] * filt[f];           // filt[f] wave-uniform

    // NOTE: keep arg = kk*(x-q)^2 in the factored form. Expanding into
    // kx^2 - 2kxq + kq^2 loses ~0.01-0.02 absolute in the exponent at
    // |terms| ~ 6e4 (fp32 ulp) -> ~1% term error, over threshold.
    float acc0 = 0.f, acc1 = 0.f, acc2 = 0.f, acc3 = 0.f;
    const float4* q4 = (const float4*)q_s;
    const float4* a4 = (const float4*)amp_s;
    #pragma unroll
    for (int j = 0; j < P / 4; ++j) {
        float4 qv = q4[j];   // ds_read_b128, same-address broadcast
        float4 av = a4[j];
        float d0 = x - qv.x;
        float d1 = x - qv.y;
        float d2 = x - qv.z;
        float d3 = x - qv.w;
        acc0 += av.x * __builtin_amdgcn_exp2f(kk * d0 * d0);
        acc1 += av.y * __builtin_amdgcn_exp2f(kk * d1 * d1);
        acc2 += av.z * __builtin_amdgcn_exp2f(kk * d2 * d2);
        acc3 += av.w * __builtin_amdgcn_exp2f(kk * d3 * d3);
    }

    out[(b * V + tid) * F + f] = (acc0 + acc1) + (acc2 + acc3);
}

extern "C" void kernel_launch(void* const* d_in, const int* in_sizes, int n_in,
                              void* d_out, int out_size, void* d_ws, size_t ws_size,
                              hipStream_t stream) {
    const float* q2     = (const float*)d_in[0]; // (32, 64)
    const float* logits = (const float*)d_in[1]; // (32, 1, 128, 64)
    const float* vol    = (const float*)d_in[2]; // (256, 1)
    const float* filt   = (const float*)d_in[3]; // (1, 128)
    const float* sigma  = (const float*)d_in[4]; // scalar
    float* out = (float*)d_out;                  // (32, 256, 128)

    extraction_kernel<<<B * F, V, 0, stream>>>(q2, logits, vol, filt, sigma, out);
}